// Round 5
// baseline (1136.721 us; speedup 1.0000x reference)
//
#include <hip/hip_runtime.h>
#include <hip/hip_bf16.h>
#include <cstdint>
#include <cstddef>

// ---------------------------------------------------------------------------
// EnhancedMultiHeadAttention on MI355X (gfx950).
// EXTERNAL dtype fp32; INTERNAL bf16 (MFMA) + fp32 softmax stats.
// R4->R5 (pass2): (a) swapped-operand QK^T MFMA => lane holds 4 consecutive k
// at fixed q => P staged with 2x ds_write_b64 (bank-optimal) instead of 8
// scalar b16 scatter writes (the 16.8M-conflict source); (b) K/V global loads
// software-pipelined one k-iter ahead in registers so they complete behind
// stage-A compute + barriers (register loads don't drain at s_barrier).
// MFMA 16x16x32 bf16 layouts (m89/m91/m120-verified):
//   A: m=lane&15, k=(lane>>4)*8+j ; B: n=lane&15, k=(lane>>4)*8+j
//   C/D: col=lane&15, row=(lane>>4)*4+reg
// ---------------------------------------------------------------------------

typedef __bf16 bf16_t;
typedef __bf16 bf16x8 __attribute__((ext_vector_type(8)));
typedef __bf16 bf16x4 __attribute__((ext_vector_type(4)));
typedef float f32x4 __attribute__((ext_vector_type(4)));

#define B_ 2
#define S_ 2048
#define E_ 1024
#define H_ 16
#define D_ 64
#define PSTR 40   // P row stride (bf16): 80 B, 16B-multiple; b64 writes and
                  // b128 reads both land min-cycles (hand-checked bank map)

static __device__ __forceinline__ f32x4 mfma16(bf16x8 a, bf16x8 b, f32x4 c) {
  return __builtin_amdgcn_mfma_f32_16x16x32_bf16(a, b, c, 0, 0, 0);
}

// ---------------- mix = softmax(head_mixing, axis=-1), fp32 ----------------
__global__ void mix_kernel(const float* __restrict__ hm, float* __restrict__ mixw) {
  int g = threadIdx.x;
  if (g < H_) {
    float v[H_]; float mx = -1e30f;
    for (int h = 0; h < H_; h++) { v[h] = hm[g * H_ + h]; mx = fmaxf(mx, v[h]); }
    float s = 0.f;
    for (int h = 0; h < H_; h++) { v[h] = __expf(v[h] - mx); s += v[h]; }
    float inv = 1.f / s;
    for (int h = 0; h < H_; h++) mixw[g * H_ + h] = v[h] * inv;
  }
}

// ---------------- V transpose: Vp[b,s,g*64+d] -> Vt[(b*16+g)*64+d][s] ------
__global__ void transpose_v_kernel(const bf16_t* __restrict__ Vp, bf16_t* __restrict__ Vt) {
  __shared__ bf16_t t[32][33];
  const int tx = threadIdx.x & 31, ty = threadIdx.x >> 5;
  const int z = blockIdx.z, b = z >> 4, g = z & 15;
  const int s0 = blockIdx.x * 32, d0 = blockIdx.y * 32;
  const bf16_t* src = Vp + (size_t)b * S_ * E_ + g * 64;
  bf16_t* dst = Vt + (size_t)z * 64 * S_;
#pragma unroll
  for (int i = 0; i < 4; i++)
    t[ty + i * 8][tx] = src[(size_t)(s0 + ty + i * 8) * E_ + d0 + tx];
  __syncthreads();
#pragma unroll
  for (int i = 0; i < 4; i++)
    dst[(size_t)(d0 + ty + i * 8) * S_ + s0 + tx] = t[tx][ty + i * 8];
}

// ---------------- GEMM: C[4096,1024] = (A @ W + bias) * scale --------------
struct GemmSec {
  const void* A; const float* bias; const float* W; void* C; float scale;
};

template <bool AF32, bool OF32>
__global__ __launch_bounds__(256) void gemm_kernel(GemmSec s0, GemmSec s1, GemmSec s2) {
  const int z = blockIdx.z;
  GemmSec p = (z == 0) ? s0 : ((z == 1) ? s1 : s2);
  const int tid = threadIdx.x;
  const int wave = tid >> 6, lane = tid & 63;
  const int ln = lane & 15, qd = lane >> 4;
  const int wm = wave >> 1, wn = wave & 1;
  const int row0 = blockIdx.y * 128, col0 = blockIdx.x * 128;

  __shared__ __align__(16) bf16_t As[128 * 32];  // [row 128][k 32]
  __shared__ __align__(16) bf16_t Bs[128 * 32];  // [n 128][k 32]

  f32x4 z4 = {0.f, 0.f, 0.f, 0.f};
  f32x4 acc[4][4];
#pragma unroll
  for (int i = 0; i < 4; i++)
#pragma unroll
    for (int j = 0; j < 4; j++) acc[i][j] = z4;

  for (int ks = 0; ks < E_ / 32; ks++) {
    const int kk = ks * 32;
#pragma unroll
    for (int cc = 0; cc < 2; cc++) {
      const int c = tid + cc * 256;
      const int r = c >> 2, kc = (c & 3) * 8;
      if (AF32) {
        const float* Af = (const float*)p.A;
        f32x4 f0 = *(const f32x4*)&Af[(size_t)(row0 + r) * E_ + kk + kc];
        f32x4 f1 = *(const f32x4*)&Af[(size_t)(row0 + r) * E_ + kk + kc + 4];
        bf16x8 v;
#pragma unroll
        for (int j = 0; j < 4; j++) { v[j] = (bf16_t)f0[j]; v[4 + j] = (bf16_t)f1[j]; }
        *(bf16x8*)&As[r * 32 + kc] = v;
      } else {
        const bf16_t* Ab = (const bf16_t*)p.A;
        *(uint4*)&As[r * 32 + kc] = *(const uint4*)&Ab[(size_t)(row0 + r) * E_ + kk + kc];
      }
    }
#pragma unroll
    for (int cc = 0; cc < 2; cc++) {
      const int c = tid + cc * 256;
      const int kr = c & 31, nc = (c >> 5) * 8;
      f32x4 g0 = *(const f32x4*)&p.W[(size_t)(kk + kr) * E_ + col0 + nc];
      f32x4 g1 = *(const f32x4*)&p.W[(size_t)(kk + kr) * E_ + col0 + nc + 4];
#pragma unroll
      for (int j = 0; j < 4; j++) {
        Bs[(nc + j) * 32 + kr]     = (bf16_t)g0[j];
        Bs[(nc + 4 + j) * 32 + kr] = (bf16_t)g1[j];
      }
    }
    __syncthreads();
    bf16x8 af[4], bfr[4];
#pragma unroll
    for (int mt = 0; mt < 4; mt++) af[mt] = *(const bf16x8*)&As[(wm * 64 + mt * 16 + ln) * 32 + qd * 8];
#pragma unroll
    for (int nt = 0; nt < 4; nt++) bfr[nt] = *(const bf16x8*)&Bs[(wn * 64 + nt * 16 + ln) * 32 + qd * 8];
#pragma unroll
    for (int mt = 0; mt < 4; mt++)
#pragma unroll
      for (int nt = 0; nt < 4; nt++)
        acc[mt][nt] = mfma16(af[mt], bfr[nt], acc[mt][nt]);
    __syncthreads();
  }
#pragma unroll
  for (int nt = 0; nt < 4; nt++) {
    int col = col0 + wn * 64 + nt * 16 + ln;
    float bias_v = p.bias[col];
#pragma unroll
    for (int mt = 0; mt < 4; mt++) {
      int row = row0 + wm * 64 + mt * 16 + qd * 4;
#pragma unroll
      for (int r = 0; r < 4; r++) {
        float v = (acc[mt][nt][r] + bias_v) * p.scale;
        if (OF32) ((float*)p.C)[(size_t)(row + r) * E_ + col] = v;
        else      ((bf16_t*)p.C)[(size_t)(row + r) * E_ + col] = (bf16_t)v;
      }
    }
  }
}

// ---------------- pass 1: softmax stats Z = m + log(l) ---------------------
// grid (32 qc, 32 bh), 256 thr; each wave owns a 16-row q-tile.
__global__ __launch_bounds__(256) void pass1_kernel(const bf16_t* __restrict__ Qp,
                                                    const bf16_t* __restrict__ Kp,
                                                    float* __restrict__ Z) {
  const int qc = blockIdx.x;
  const int bh = blockIdx.y;
  const int b = bh >> 4, h = bh & 15;
  const int tid = threadIdx.x;
  const int wave = tid >> 6, lane = tid & 63;
  const int ln = lane & 15, qd = lane >> 4;
  const size_t rowbase = (size_t)b * S_;
  const int qbase = qc * 64 + wave * 16;

  bf16x8 qf[2];
#pragma unroll
  for (int db = 0; db < 2; db++)
    qf[db] = *(const bf16x8*)&Qp[(rowbase + qbase + ln) * E_ + h * 64 + db * 32 + qd * 8];

  float m[4], l[4];
#pragma unroll
  for (int r = 0; r < 4; r++) { m[r] = -1e30f; l[r] = 0.f; }

  for (int kt = 0; kt < S_ / 64; kt++) {
    bf16x8 kf[4][2];
#pragma unroll
    for (int nt = 0; nt < 4; nt++)
#pragma unroll
      for (int db = 0; db < 2; db++)
        kf[nt][db] = *(const bf16x8*)&Kp[(rowbase + kt * 64 + nt * 16 + ln) * E_ + h * 64 + db * 32 + qd * 8];
    f32x4 sc[4];
#pragma unroll
    for (int nt = 0; nt < 4; nt++) {
      f32x4 c0 = {0.f, 0.f, 0.f, 0.f};
      c0 = mfma16(qf[0], kf[nt][0], c0);
      sc[nt] = mfma16(qf[1], kf[nt][1], c0);
    }
#pragma unroll
    for (int r = 0; r < 4; r++) {
      float tmax = fmaxf(fmaxf(sc[0][r], sc[1][r]), fmaxf(sc[2][r], sc[3][r]));
      float mn = fmaxf(m[r], tmax);
      float add = __expf(sc[0][r] - mn) + __expf(sc[1][r] - mn) +
                  __expf(sc[2][r] - mn) + __expf(sc[3][r] - mn);
      l[r] = l[r] * __expf(m[r] - mn) + add;
      m[r] = mn;
    }
  }
#pragma unroll
  for (int r = 0; r < 4; r++) {
    float mm = m[r], ll = l[r];
    for (int mask = 1; mask < 16; mask <<= 1) {
      float mo = __shfl_xor(mm, mask);
      float lo = __shfl_xor(ll, mask);
      float mn = fmaxf(mm, mo);
      ll = ll * __expf(mm - mn) + lo * __expf(mo - mn);
      mm = mn;
    }
    if (ln == 0) {
      int q = qbase + qd * 4 + r;
      Z[(size_t)bh * S_ + q] = mm + __logf(ll);
    }
  }
}

// ---------------- pass 2: p=exp(s-Z), head-mix, PV -> ctx bf16 -------------
// 256 blocks x 1024 thr (16 waves). wave w owns source/out head w for the
// block's 16-row q-tile. K/V register-prefetched one k-iter ahead.
__global__ __launch_bounds__(1024, 4) void pass2_kernel(const bf16_t* __restrict__ Qp,
                                                        const bf16_t* __restrict__ Kp,
                                                        const bf16_t* __restrict__ Vt,
                                                        const float* __restrict__ Z,
                                                        const float* __restrict__ mixw,
                                                        bf16_t* __restrict__ ctx) {
  const int id = blockIdx.x;            // 0..255
  const int b = id >> 7;
  const int qt = id & 127;
  const int q0 = qt * 16;

  const int tid = threadIdx.x;
  const int wave = tid >> 6, lane = tid & 63;
  const int ln = lane & 15, qd = lane >> 4;
  const int h = wave;                   // this wave's head

  __shared__ __align__(16) bf16_t Plds[H_ * 16 * PSTR];  // [h][q16][k PSTR]

  const size_t rowbase = (size_t)b * S_;
  const bf16_t* Krow = &Kp[0] + (rowbase)*E_ + h * 64;          // + k*E_
  const bf16_t* Vrow = &Vt[((size_t)((b * H_ + h) * 64)) * S_]; // + d*S_ + k

  bf16x8 qf[2];
#pragma unroll
  for (int db = 0; db < 2; db++)
    qf[db] = *(const bf16x8*)&Qp[(rowbase + q0 + ln) * E_ + h * 64 + db * 32 + qd * 8];

  // Z for this lane's q column (col = q0 + ln after operand swap)
  const float Zl = Z[((size_t)(b * H_ + h)) * S_ + q0 + ln];

  float wreg[16];
#pragma unroll
  for (int hh = 0; hh < 16; hh++) wreg[hh] = mixw[h * 16 + hh];

  f32x4 z4 = {0.f, 0.f, 0.f, 0.f};
  f32x4 cacc[4];
#pragma unroll
  for (int nt = 0; nt < 4; nt++) cacc[nt] = z4;

  // ---- prefetch k-iter 0
  bf16x8 kf_c[2][2], kf_n[2][2];
  bf16x8 vf_c[4], vf_n[4];
#pragma unroll
  for (int n2 = 0; n2 < 2; n2++)
#pragma unroll
    for (int db = 0; db < 2; db++)
      kf_c[n2][db] = *(const bf16x8*)&Krow[(size_t)(n2 * 16 + ln) * E_ + db * 32 + qd * 8];
#pragma unroll
  for (int nt = 0; nt < 4; nt++)
    vf_c[nt] = *(const bf16x8*)&Vrow[(size_t)(nt * 16 + ln) * S_ + qd * 8];

  for (int ks = 0; ks < S_ / 32; ks++) {
    const int kb = ks * 32;
    const int kbn = (ks + 1 < S_ / 32) ? kb + 32 : kb;   // clamp (redundant last)
    // ---- issue next-iter loads (complete behind compute + barriers)
#pragma unroll
    for (int n2 = 0; n2 < 2; n2++)
#pragma unroll
      for (int db = 0; db < 2; db++)
        kf_n[n2][db] = *(const bf16x8*)&Krow[(size_t)(kbn + n2 * 16 + ln) * E_ + db * 32 + qd * 8];
#pragma unroll
    for (int nt = 0; nt < 4; nt++)
      vf_n[nt] = *(const bf16x8*)&Vrow[(size_t)(nt * 16 + ln) * S_ + kbn + qd * 8];

    // ---- stage A (swapped operands): D[col=q=ln][row=k] => b64 P-writes
#pragma unroll
    for (int n2 = 0; n2 < 2; n2++) {
      f32x4 c0 = {-Zl, -Zl, -Zl, -Zl};
      c0 = mfma16(kf_c[n2][0], qf[0], c0);
      c0 = mfma16(kf_c[n2][1], qf[1], c0);
      bf16x4 pw;
#pragma unroll
      for (int r = 0; r < 4; r++) pw[r] = (bf16_t)__expf(c0[r]);
      // P[h][q=ln][k = n2*16 + qd*4 .. +3]
      *(bf16x4*)&Plds[(h * 16 + ln) * PSTR + n2 * 16 + qd * 4] = pw;
    }
    __syncthreads();
    // ---- stage B: mix all 16 source heads for out-head h, then PV
    float ma[8];
#pragma unroll
    for (int j = 0; j < 8; j++) ma[j] = 0.f;
#pragma unroll
    for (int hh = 0; hh < H_; hh++) {
      bf16x8 pf = *(const bf16x8*)&Plds[(hh * 16 + ln) * PSTR + qd * 8];
      float w = wreg[hh];
#pragma unroll
      for (int j = 0; j < 8; j++) ma[j] += w * (float)pf[j];
    }
    bf16x8 af;
#pragma unroll
    for (int j = 0; j < 8; j++) af[j] = (bf16_t)ma[j];
#pragma unroll
    for (int nt = 0; nt < 4; nt++)
      cacc[nt] = mfma16(af, vf_c[nt], cacc[nt]);
    __syncthreads();
    // ---- rotate prefetch
#pragma unroll
    for (int n2 = 0; n2 < 2; n2++)
#pragma unroll
      for (int db = 0; db < 2; db++) kf_c[n2][db] = kf_n[n2][db];
#pragma unroll
    for (int nt = 0; nt < 4; nt++) vf_c[nt] = vf_n[nt];
  }
#pragma unroll
  for (int nt = 0; nt < 4; nt++)
#pragma unroll
    for (int r = 0; r < 4; r++)
      ctx[(rowbase + q0 + qd * 4 + r) * E_ + h * 64 + nt * 16 + ln] = (bf16_t)cacc[nt][r];
}

// ---------------------------------------------------------------------------
extern "C" void kernel_launch(void* const* d_in, const int* in_sizes, int n_in,
                              void* d_out, int out_size, void* d_ws, size_t ws_size,
                              hipStream_t stream) {
  const float* query = (const float*)d_in[0];
  const float* key_  = (const float*)d_in[1];
  const float* value = (const float*)d_in[2];
  const float* Wq = (const float*)d_in[3];
  const float* bq = (const float*)d_in[4];
  const float* Wk = (const float*)d_in[5];
  const float* bk = (const float*)d_in[6];
  const float* Wv = (const float*)d_in[7];
  const float* bv = (const float*)d_in[8];
  const float* hm = (const float*)d_in[9];
  const float* Wo = (const float*)d_in[10];
  const float* bo = (const float*)d_in[11];
  float* out = (float*)d_out;

  char* ws = (char*)d_ws;
  size_t off = 0;
  auto alloc = [&](size_t bytes) -> void* {
    void* p = ws + off;
    off += (bytes + 255) & ~(size_t)255;
    return p;
  };
  float*  MIXW = (float*) alloc(256 * 4);
  float*  Zb   = (float*) alloc((size_t)B_ * H_ * S_ * 4);  // 256 KB
  bf16_t* Qp   = (bf16_t*)alloc((size_t)B_ * S_ * E_ * 2);  // 8.4 MB (scaled 1/8)
  bf16_t* Kp   = (bf16_t*)alloc((size_t)B_ * S_ * E_ * 2);  // 8.4 MB
  bf16_t* Vp   = (bf16_t*)alloc((size_t)B_ * S_ * E_ * 2);  // 8.4 MB
  bf16_t* Vtt  = (bf16_t*)alloc((size_t)B_ * S_ * E_ * 2);  // 8.4 MB [b,g,d,s]
  bf16_t* CTX  = Vp;  // alias: Vp dead after transpose_v (stream-ordered)
  (void)in_sizes; (void)n_in; (void)out_size; (void)ws_size;

  mix_kernel<<<1, 256, 0, stream>>>(hm, MIXW);

  GemmSec sq{query, bq, Wq, Qp, 0.125f};
  GemmSec sk{key_,  bk, Wk, Kp, 1.f};
  GemmSec sv{value, bv, Wv, Vp, 1.f};
  gemm_kernel<true, false><<<dim3(8, 32, 3), 256, 0, stream>>>(sq, sk, sv);

  transpose_v_kernel<<<dim3(64, 2, 32), 256, 0, stream>>>(Vp, Vtt);
  pass1_kernel<<<dim3(32, 32, 1), 256, 0, stream>>>(Qp, Kp, Zb);
  pass2_kernel<<<dim3(256, 1, 1), 1024, 0, stream>>>(Qp, Kp, Vtt, Zb, MIXW, CTX);

  GemmSec so{CTX, bo, Wo, out, 1.f};
  gemm_kernel<false, true><<<dim3(8, 32, 1), 256, 0, stream>>>(so, so, so);
}

// Round 6
// 930.380 us; speedup vs baseline: 1.2218x; 1.2218x over previous
//
#include <hip/hip_runtime.h>
#include <hip/hip_bf16.h>
#include <cstdint>
#include <cstddef>

// ---------------------------------------------------------------------------
// EnhancedMultiHeadAttention on MI355X (gfx950).
// EXTERNAL dtype fp32; INTERNAL bf16 (MFMA) + fp32 softmax stats.
// R5->R6: (a) drop register double-buffer prefetch (R5 spilled to scratch:
// WRITE_SIZE 1.8 GB, FETCH 1.3 GB, 2.2x slower); (b) pass2 = 512 blocks x 8
// waves: each block computes ALL 16 src-head P tiles (wave w does heads w,w+8
// -- duplicated MFMA is free at 1.7% MfmaUtil) but only 8 out-heads
// (g = half*8 + w) => 2 independent barrier groups per CU to hide latency;
// (c) GEMM LDS row stride 32->40 to fix staging bank conflicts.
// MFMA 16x16x32 bf16 layouts (m89/m91/m120-verified):
//   A: m=lane&15, k=(lane>>4)*8+j ; B: n=lane&15, k=(lane>>4)*8+j
//   C/D: col=lane&15, row=(lane>>4)*4+reg
// ---------------------------------------------------------------------------

typedef __bf16 bf16_t;
typedef __bf16 bf16x8 __attribute__((ext_vector_type(8)));
typedef __bf16 bf16x4 __attribute__((ext_vector_type(4)));
typedef float f32x4 __attribute__((ext_vector_type(4)));

#define B_ 2
#define S_ 2048
#define E_ 1024
#define H_ 16
#define D_ 64
#define PSTR 40   // P row stride (bf16): 80 B
#define GSTR 40   // GEMM LDS row stride (bf16)

static __device__ __forceinline__ f32x4 mfma16(bf16x8 a, bf16x8 b, f32x4 c) {
  return __builtin_amdgcn_mfma_f32_16x16x32_bf16(a, b, c, 0, 0, 0);
}

// ---------------- mix = softmax(head_mixing, axis=-1), fp32 ----------------
__global__ void mix_kernel(const float* __restrict__ hm, float* __restrict__ mixw) {
  int g = threadIdx.x;
  if (g < H_) {
    float v[H_]; float mx = -1e30f;
    for (int h = 0; h < H_; h++) { v[h] = hm[g * H_ + h]; mx = fmaxf(mx, v[h]); }
    float s = 0.f;
    for (int h = 0; h < H_; h++) { v[h] = __expf(v[h] - mx); s += v[h]; }
    float inv = 1.f / s;
    for (int h = 0; h < H_; h++) mixw[g * H_ + h] = v[h] * inv;
  }
}

// ---------------- V transpose: Vp[b,s,g*64+d] -> Vt[(b*16+g)*64+d][s] ------
__global__ void transpose_v_kernel(const bf16_t* __restrict__ Vp, bf16_t* __restrict__ Vt) {
  __shared__ bf16_t t[32][33];
  const int tx = threadIdx.x & 31, ty = threadIdx.x >> 5;
  const int z = blockIdx.z, b = z >> 4, g = z & 15;
  const int s0 = blockIdx.x * 32, d0 = blockIdx.y * 32;
  const bf16_t* src = Vp + (size_t)b * S_ * E_ + g * 64;
  bf16_t* dst = Vt + (size_t)z * 64 * S_;
#pragma unroll
  for (int i = 0; i < 4; i++)
    t[ty + i * 8][tx] = src[(size_t)(s0 + ty + i * 8) * E_ + d0 + tx];
  __syncthreads();
#pragma unroll
  for (int i = 0; i < 4; i++)
    dst[(size_t)(d0 + ty + i * 8) * S_ + s0 + tx] = t[tx][ty + i * 8];
}

// ---------------- GEMM: C[4096,1024] = (A @ W + bias) * scale --------------
struct GemmSec {
  const void* A; const float* bias; const float* W; void* C; float scale;
};

template <bool AF32, bool OF32>
__global__ __launch_bounds__(256) void gemm_kernel(GemmSec s0, GemmSec s1, GemmSec s2) {
  const int z = blockIdx.z;
  GemmSec p = (z == 0) ? s0 : ((z == 1) ? s1 : s2);
  const int tid = threadIdx.x;
  const int wave = tid >> 6, lane = tid & 63;
  const int ln = lane & 15, qd = lane >> 4;
  const int wm = wave >> 1, wn = wave & 1;
  const int row0 = blockIdx.y * 128, col0 = blockIdx.x * 128;

  __shared__ __align__(16) bf16_t As[128 * GSTR];  // [row 128][k 32 pad 40]
  __shared__ __align__(16) bf16_t Bs[128 * GSTR];  // [n 128][k 32 pad 40]

  f32x4 z4 = {0.f, 0.f, 0.f, 0.f};
  f32x4 acc[4][4];
#pragma unroll
  for (int i = 0; i < 4; i++)
#pragma unroll
    for (int j = 0; j < 4; j++) acc[i][j] = z4;

  for (int ks = 0; ks < E_ / 32; ks++) {
    const int kk = ks * 32;
#pragma unroll
    for (int cc = 0; cc < 2; cc++) {
      const int c = tid + cc * 256;
      const int r = c >> 2, kc = (c & 3) * 8;
      if (AF32) {
        const float* Af = (const float*)p.A;
        f32x4 f0 = *(const f32x4*)&Af[(size_t)(row0 + r) * E_ + kk + kc];
        f32x4 f1 = *(const f32x4*)&Af[(size_t)(row0 + r) * E_ + kk + kc + 4];
        bf16x8 v;
#pragma unroll
        for (int j = 0; j < 4; j++) { v[j] = (bf16_t)f0[j]; v[4 + j] = (bf16_t)f1[j]; }
        *(bf16x8*)&As[r * GSTR + kc] = v;
      } else {
        const bf16_t* Ab = (const bf16_t*)p.A;
        *(uint4*)&As[r * GSTR + kc] = *(const uint4*)&Ab[(size_t)(row0 + r) * E_ + kk + kc];
      }
    }
#pragma unroll
    for (int cc = 0; cc < 2; cc++) {
      const int c = tid + cc * 256;
      const int kr = c & 31, nc = (c >> 5) * 8;
      f32x4 g0 = *(const f32x4*)&p.W[(size_t)(kk + kr) * E_ + col0 + nc];
      f32x4 g1 = *(const f32x4*)&p.W[(size_t)(kk + kr) * E_ + col0 + nc + 4];
#pragma unroll
      for (int j = 0; j < 4; j++) {
        Bs[(nc + j) * GSTR + kr]     = (bf16_t)g0[j];
        Bs[(nc + 4 + j) * GSTR + kr] = (bf16_t)g1[j];
      }
    }
    __syncthreads();
    bf16x8 af[4], bfr[4];
#pragma unroll
    for (int mt = 0; mt < 4; mt++) af[mt] = *(const bf16x8*)&As[(wm * 64 + mt * 16 + ln) * GSTR + qd * 8];
#pragma unroll
    for (int nt = 0; nt < 4; nt++) bfr[nt] = *(const bf16x8*)&Bs[(wn * 64 + nt * 16 + ln) * GSTR + qd * 8];
#pragma unroll
    for (int mt = 0; mt < 4; mt++)
#pragma unroll
      for (int nt = 0; nt < 4; nt++)
        acc[mt][nt] = mfma16(af[mt], bfr[nt], acc[mt][nt]);
    __syncthreads();
  }
#pragma unroll
  for (int nt = 0; nt < 4; nt++) {
    int col = col0 + wn * 64 + nt * 16 + ln;
    float bias_v = p.bias[col];
#pragma unroll
    for (int mt = 0; mt < 4; mt++) {
      int row = row0 + wm * 64 + mt * 16 + qd * 4;
#pragma unroll
      for (int r = 0; r < 4; r++) {
        float v = (acc[mt][nt][r] + bias_v) * p.scale;
        if (OF32) ((float*)p.C)[(size_t)(row + r) * E_ + col] = v;
        else      ((bf16_t*)p.C)[(size_t)(row + r) * E_ + col] = (bf16_t)v;
      }
    }
  }
}

// ---------------- pass 1: softmax stats Z = m + log(l) ---------------------
__global__ __launch_bounds__(256) void pass1_kernel(const bf16_t* __restrict__ Qp,
                                                    const bf16_t* __restrict__ Kp,
                                                    float* __restrict__ Z) {
  const int qc = blockIdx.x;
  const int bh = blockIdx.y;
  const int b = bh >> 4, h = bh & 15;
  const int tid = threadIdx.x;
  const int wave = tid >> 6, lane = tid & 63;
  const int ln = lane & 15, qd = lane >> 4;
  const size_t rowbase = (size_t)b * S_;
  const int qbase = qc * 64 + wave * 16;

  bf16x8 qf[2];
#pragma unroll
  for (int db = 0; db < 2; db++)
    qf[db] = *(const bf16x8*)&Qp[(rowbase + qbase + ln) * E_ + h * 64 + db * 32 + qd * 8];

  float m[4], l[4];
#pragma unroll
  for (int r = 0; r < 4; r++) { m[r] = -1e30f; l[r] = 0.f; }

  for (int kt = 0; kt < S_ / 64; kt++) {
    bf16x8 kf[4][2];
#pragma unroll
    for (int nt = 0; nt < 4; nt++)
#pragma unroll
      for (int db = 0; db < 2; db++)
        kf[nt][db] = *(const bf16x8*)&Kp[(rowbase + kt * 64 + nt * 16 + ln) * E_ + h * 64 + db * 32 + qd * 8];
    f32x4 sc[4];
#pragma unroll
    for (int nt = 0; nt < 4; nt++) {
      f32x4 c0 = {0.f, 0.f, 0.f, 0.f};
      c0 = mfma16(qf[0], kf[nt][0], c0);
      sc[nt] = mfma16(qf[1], kf[nt][1], c0);
    }
#pragma unroll
    for (int r = 0; r < 4; r++) {
      float tmax = fmaxf(fmaxf(sc[0][r], sc[1][r]), fmaxf(sc[2][r], sc[3][r]));
      float mn = fmaxf(m[r], tmax);
      float add = __expf(sc[0][r] - mn) + __expf(sc[1][r] - mn) +
                  __expf(sc[2][r] - mn) + __expf(sc[3][r] - mn);
      l[r] = l[r] * __expf(m[r] - mn) + add;
      m[r] = mn;
    }
  }
#pragma unroll
  for (int r = 0; r < 4; r++) {
    float mm = m[r], ll = l[r];
    for (int mask = 1; mask < 16; mask <<= 1) {
      float mo = __shfl_xor(mm, mask);
      float lo = __shfl_xor(ll, mask);
      float mn = fmaxf(mm, mo);
      ll = ll * __expf(mm - mn) + lo * __expf(mo - mn);
      mm = mn;
    }
    if (ln == 0) {
      int q = qbase + qd * 4 + r;
      Z[(size_t)bh * S_ + q] = mm + __logf(ll);
    }
  }
}

// ---------------- pass 2: p=exp(s-Z), head-mix, PV -> ctx bf16 -------------
// 512 blocks x 512 thr (8 waves): id = (qt<<2)|(b<<1)|half. Wave w computes
// P for src heads w and w+8 (stage A, swapped-operand MFMA -> b64 P-writes),
// then mixes+PV for out-head g = half*8 + w. 2 blocks/CU overlap barriers.
__global__ __launch_bounds__(512, 4) void pass2_kernel(const bf16_t* __restrict__ Qp,
                                                       const bf16_t* __restrict__ Kp,
                                                       const bf16_t* __restrict__ Vt,
                                                       const float* __restrict__ Z,
                                                       const float* __restrict__ mixw,
                                                       bf16_t* __restrict__ ctx) {
  const int id = blockIdx.x;            // 0..511
  const int half = id & 1;
  const int b = (id >> 1) & 1;
  const int qt = id >> 2;               // 0..127
  const int q0 = qt * 16;

  const int tid = threadIdx.x;
  const int wave = tid >> 6, lane = tid & 63;
  const int ln = lane & 15, qd = lane >> 4;
  const int g = half * 8 + wave;        // out-head

  __shared__ __align__(16) bf16_t Plds[H_ * 16 * PSTR];  // [h][q16][k PSTR]

  const size_t rowbase = (size_t)b * S_;
  const bf16_t* Vrow = &Vt[((size_t)((b * H_ + g) * 64)) * S_]; // + d*S_ + k

  // stage-A state for src heads wave, wave+8
  bf16x8 qf[2][2];
  float Zl[2];
#pragma unroll
  for (int e = 0; e < 2; e++) {
    const int hh = wave + e * 8;
#pragma unroll
    for (int db = 0; db < 2; db++)
      qf[e][db] = *(const bf16x8*)&Qp[(rowbase + q0 + ln) * E_ + hh * 64 + db * 32 + qd * 8];
    Zl[e] = Z[((size_t)(b * H_ + hh)) * S_ + q0 + ln];
  }

  float wreg[16];
#pragma unroll
  for (int hh = 0; hh < 16; hh++) wreg[hh] = mixw[g * 16 + hh];

  f32x4 z4 = {0.f, 0.f, 0.f, 0.f};
  f32x4 cacc[4];
#pragma unroll
  for (int nt = 0; nt < 4; nt++) cacc[nt] = z4;

  for (int ks = 0; ks < S_ / 32; ks++) {
    const int kb = ks * 32;
    // ---- issue V loads early: consumed after barrier+mix (latency covered)
    bf16x8 vf[4];
#pragma unroll
    for (int nt = 0; nt < 4; nt++)
      vf[nt] = *(const bf16x8*)&Vrow[(size_t)(nt * 16 + ln) * S_ + kb + qd * 8];
    // ---- stage A: P for src heads wave, wave+8 (swapped operands => lane
    //      holds 4 consecutive k at fixed q=ln => b64 writes)
#pragma unroll
    for (int e = 0; e < 2; e++) {
      const int hh = wave + e * 8;
      bf16x8 kf[2][2];
#pragma unroll
      for (int n2 = 0; n2 < 2; n2++)
#pragma unroll
        for (int db = 0; db < 2; db++)
          kf[n2][db] = *(const bf16x8*)&Kp[(rowbase + kb + n2 * 16 + ln) * E_ + hh * 64 + db * 32 + qd * 8];
#pragma unroll
      for (int n2 = 0; n2 < 2; n2++) {
        f32x4 c0 = {-Zl[e], -Zl[e], -Zl[e], -Zl[e]};
        c0 = mfma16(kf[n2][0], qf[e][0], c0);
        c0 = mfma16(kf[n2][1], qf[e][1], c0);
        bf16x4 pw;
#pragma unroll
        for (int r = 0; r < 4; r++) pw[r] = (bf16_t)__expf(c0[r]);
        *(bf16x4*)&Plds[(hh * 16 + ln) * PSTR + n2 * 16 + qd * 4] = pw;
      }
    }
    __syncthreads();
    // ---- stage B: mix all 16 src heads for out-head g, then PV
    float ma[8];
#pragma unroll
    for (int j = 0; j < 8; j++) ma[j] = 0.f;
#pragma unroll
    for (int hh = 0; hh < H_; hh++) {
      bf16x8 pf = *(const bf16x8*)&Plds[(hh * 16 + ln) * PSTR + qd * 8];
      float w = wreg[hh];
#pragma unroll
      for (int j = 0; j < 8; j++) ma[j] += w * (float)pf[j];
    }
    bf16x8 af;
#pragma unroll
    for (int j = 0; j < 8; j++) af[j] = (bf16_t)ma[j];
#pragma unroll
    for (int nt = 0; nt < 4; nt++)
      cacc[nt] = mfma16(af, vf[nt], cacc[nt]);
    __syncthreads();
  }
#pragma unroll
  for (int nt = 0; nt < 4; nt++)
#pragma unroll
    for (int r = 0; r < 4; r++)
      ctx[(rowbase + q0 + qd * 4 + r) * E_ + g * 64 + nt * 16 + ln] = (bf16_t)cacc[nt][r];
}

// ---------------------------------------------------------------------------
extern "C" void kernel_launch(void* const* d_in, const int* in_sizes, int n_in,
                              void* d_out, int out_size, void* d_ws, size_t ws_size,
                              hipStream_t stream) {
  const float* query = (const float*)d_in[0];
  const float* key_  = (const float*)d_in[1];
  const float* value = (const float*)d_in[2];
  const float* Wq = (const float*)d_in[3];
  const float* bq = (const float*)d_in[4];
  const float* Wk = (const float*)d_in[5];
  const float* bk = (const float*)d_in[6];
  const float* Wv = (const float*)d_in[7];
  const float* bv = (const float*)d_in[8];
  const float* hm = (const float*)d_in[9];
  const float* Wo = (const float*)d_in[10];
  const float* bo = (const float*)d_in[11];
  float* out = (float*)d_out;

  char* ws = (char*)d_ws;
  size_t off = 0;
  auto alloc = [&](size_t bytes) -> void* {
    void* p = ws + off;
    off += (bytes + 255) & ~(size_t)255;
    return p;
  };
  float*  MIXW = (float*) alloc(256 * 4);
  float*  Zb   = (float*) alloc((size_t)B_ * H_ * S_ * 4);  // 256 KB
  bf16_t* Qp   = (bf16_t*)alloc((size_t)B_ * S_ * E_ * 2);  // 8.4 MB (scaled 1/8)
  bf16_t* Kp   = (bf16_t*)alloc((size_t)B_ * S_ * E_ * 2);  // 8.4 MB
  bf16_t* Vp   = (bf16_t*)alloc((size_t)B_ * S_ * E_ * 2);  // 8.4 MB
  bf16_t* Vtt  = (bf16_t*)alloc((size_t)B_ * S_ * E_ * 2);  // 8.4 MB [b,g,d,s]
  bf16_t* CTX  = Vp;  // alias: Vp dead after transpose_v (stream-ordered)
  (void)in_sizes; (void)n_in; (void)out_size; (void)ws_size;

  mix_kernel<<<1, 256, 0, stream>>>(hm, MIXW);

  GemmSec sq{query, bq, Wq, Qp, 0.125f};
  GemmSec sk{key_,  bk, Wk, Kp, 1.f};
  GemmSec sv{value, bv, Wv, Vp, 1.f};
  gemm_kernel<true, false><<<dim3(8, 32, 3), 256, 0, stream>>>(sq, sk, sv);

  transpose_v_kernel<<<dim3(64, 2, 32), 256, 0, stream>>>(Vp, Vtt);
  pass1_kernel<<<dim3(32, 32, 1), 256, 0, stream>>>(Qp, Kp, Zb);
  pass2_kernel<<<dim3(512, 1, 1), 512, 0, stream>>>(Qp, Kp, Vtt, Zb, MIXW, CTX);

  GemmSec so{CTX, bo, Wo, out, 1.f};
  gemm_kernel<false, true><<<dim3(8, 32, 1), 256, 0, stream>>>(so, so, so);
}

// Round 8
// 818.131 us; speedup vs baseline: 1.3894x; 1.1372x over previous
//
#include <hip/hip_runtime.h>
#include <hip/hip_bf16.h>
#include <cstdint>
#include <cstddef>

// ---------------------------------------------------------------------------
// EnhancedMultiHeadAttention on MI355X (gfx950).
// EXTERNAL dtype fp32; INTERNAL bf16 (MFMA) + fp32 softmax stats.
// R7->R8: NaN root cause = 0 x (uninit LDS) in B1's zero-masked upper-K reads
// (0*NaN=NaN) + 4-elem OOB read at kk=31. Fix: zero-init Pl (+16 guard) once;
// B1 switched from f16 MFMA to the VERIFIED bf16 MFMA with bf16 hi+lo mix
// split (residual 2^-16, no denormal flush risk).
// pass2 = 3-stage MFMA pipeline, 512 blocks x 8 waves, 2 blocks/CU:
//   A : QK^T (swapped operands) -> exp -> P[q][k][h] bf16 in LDS
//   B1: mixed[g][q][k] = (mix_hi + mix_lo) @ P  via bf16 MFMA (upper K x0)
//   B2: PV: wave owns out-heads 2w,2w+1: 1 b128 MX read + 4 V + 4 MFMA each
// MFMA 16x16x32 bf16 layouts (m89/m91/m120-verified):
//   A: m=lane&15, k=(lane>>4)*8+j ; B: n=lane&15, k=(lane>>4)*8+j
//   C/D: col=lane&15, row=(lane>>4)*4+reg
// ---------------------------------------------------------------------------

typedef __bf16 bf16_t;
typedef __bf16 bf16x8 __attribute__((ext_vector_type(8)));
typedef __bf16 bf16x4 __attribute__((ext_vector_type(4)));
typedef float f32x4 __attribute__((ext_vector_type(4)));

#define B_ 2
#define S_ 2048
#define E_ 1024
#define H_ 16
#define D_ 64
#define GSTR 40    // GEMM LDS row stride (bf16)
#define PQS 648    // P q-stride (bf16): dword-stride 324 %32 = 4 -> spread banks
#define PKS 20     // P k-stride (bf16): h dim 16 + pad 4
#define MXS 48     // mixed row stride (bf16): 96 B, 16B-mult

static __device__ __forceinline__ f32x4 mfma16(bf16x8 a, bf16x8 b, f32x4 c) {
  return __builtin_amdgcn_mfma_f32_16x16x32_bf16(a, b, c, 0, 0, 0);
}

// ---------------- mix = softmax(head_mixing): bf16 hi + lo -----------------
__global__ void mix_kernel(const float* __restrict__ hm,
                           bf16_t* __restrict__ mixh, bf16_t* __restrict__ mixl) {
  int g = threadIdx.x;
  if (g < H_) {
    float v[H_]; float mx = -1e30f;
    for (int h = 0; h < H_; h++) { v[h] = hm[g * H_ + h]; mx = fmaxf(mx, v[h]); }
    float s = 0.f;
    for (int h = 0; h < H_; h++) { v[h] = __expf(v[h] - mx); s += v[h]; }
    float inv = 1.f / s;
    for (int h = 0; h < H_; h++) {
      float w = v[h] * inv;
      bf16_t hi = (bf16_t)w;
      mixh[g * H_ + h] = hi;
      mixl[g * H_ + h] = (bf16_t)(w - (float)hi);
    }
  }
}

// ---------------- V transpose: Vp[b,s,g*64+d] -> Vt[(b*16+g)*64+d][s] ------
__global__ void transpose_v_kernel(const bf16_t* __restrict__ Vp, bf16_t* __restrict__ Vt) {
  __shared__ bf16_t t[32][33];
  const int tx = threadIdx.x & 31, ty = threadIdx.x >> 5;
  const int z = blockIdx.z, b = z >> 4, g = z & 15;
  const int s0 = blockIdx.x * 32, d0 = blockIdx.y * 32;
  const bf16_t* src = Vp + (size_t)b * S_ * E_ + g * 64;
  bf16_t* dst = Vt + (size_t)z * 64 * S_;
#pragma unroll
  for (int i = 0; i < 4; i++)
    t[ty + i * 8][tx] = src[(size_t)(s0 + ty + i * 8) * E_ + d0 + tx];
  __syncthreads();
#pragma unroll
  for (int i = 0; i < 4; i++)
    dst[(size_t)(d0 + ty + i * 8) * S_ + s0 + tx] = t[tx][ty + i * 8];
}

// ---------------- GEMM: C[4096,1024] = (A @ W + bias) * scale --------------
struct GemmSec {
  const void* A; const float* bias; const float* W; void* C; float scale;
};

template <bool AF32, bool OF32>
__global__ __launch_bounds__(256) void gemm_kernel(GemmSec s0, GemmSec s1, GemmSec s2) {
  const int z = blockIdx.z;
  GemmSec p = (z == 0) ? s0 : ((z == 1) ? s1 : s2);
  const int tid = threadIdx.x;
  const int wave = tid >> 6, lane = tid & 63;
  const int ln = lane & 15, qd = lane >> 4;
  const int wm = wave >> 1, wn = wave & 1;
  const int row0 = blockIdx.y * 128, col0 = blockIdx.x * 128;

  __shared__ __align__(16) bf16_t As[128 * GSTR];
  __shared__ __align__(16) bf16_t Bs[128 * GSTR];

  f32x4 z4 = {0.f, 0.f, 0.f, 0.f};
  f32x4 acc[4][4];
#pragma unroll
  for (int i = 0; i < 4; i++)
#pragma unroll
    for (int j = 0; j < 4; j++) acc[i][j] = z4;

  for (int ks = 0; ks < E_ / 32; ks++) {
    const int kk = ks * 32;
#pragma unroll
    for (int cc = 0; cc < 2; cc++) {
      const int c = tid + cc * 256;
      const int r = c >> 2, kc = (c & 3) * 8;
      if (AF32) {
        const float* Af = (const float*)p.A;
        f32x4 f0 = *(const f32x4*)&Af[(size_t)(row0 + r) * E_ + kk + kc];
        f32x4 f1 = *(const f32x4*)&Af[(size_t)(row0 + r) * E_ + kk + kc + 4];
        bf16x8 v;
#pragma unroll
        for (int j = 0; j < 4; j++) { v[j] = (bf16_t)f0[j]; v[4 + j] = (bf16_t)f1[j]; }
        *(bf16x8*)&As[r * GSTR + kc] = v;
      } else {
        const bf16_t* Ab = (const bf16_t*)p.A;
        *(uint4*)&As[r * GSTR + kc] = *(const uint4*)&Ab[(size_t)(row0 + r) * E_ + kk + kc];
      }
    }
#pragma unroll
    for (int cc = 0; cc < 2; cc++) {
      const int c = tid + cc * 256;
      const int kr = c & 31, nc = (c >> 5) * 8;
      f32x4 g0 = *(const f32x4*)&p.W[(size_t)(kk + kr) * E_ + col0 + nc];
      f32x4 g1 = *(const f32x4*)&p.W[(size_t)(kk + kr) * E_ + col0 + nc + 4];
#pragma unroll
      for (int j = 0; j < 4; j++) {
        Bs[(nc + j) * GSTR + kr]     = (bf16_t)g0[j];
        Bs[(nc + 4 + j) * GSTR + kr] = (bf16_t)g1[j];
      }
    }
    __syncthreads();
    bf16x8 af[4], bfr[4];
#pragma unroll
    for (int mt = 0; mt < 4; mt++) af[mt] = *(const bf16x8*)&As[(wm * 64 + mt * 16 + ln) * GSTR + qd * 8];
#pragma unroll
    for (int nt = 0; nt < 4; nt++) bfr[nt] = *(const bf16x8*)&Bs[(wn * 64 + nt * 16 + ln) * GSTR + qd * 8];
#pragma unroll
    for (int mt = 0; mt < 4; mt++)
#pragma unroll
      for (int nt = 0; nt < 4; nt++)
        acc[mt][nt] = mfma16(af[mt], bfr[nt], acc[mt][nt]);
    __syncthreads();
  }
#pragma unroll
  for (int nt = 0; nt < 4; nt++) {
    int col = col0 + wn * 64 + nt * 16 + ln;
    float bias_v = p.bias[col];
#pragma unroll
    for (int mt = 0; mt < 4; mt++) {
      int row = row0 + wm * 64 + mt * 16 + qd * 4;
#pragma unroll
      for (int r = 0; r < 4; r++) {
        float v = (acc[mt][nt][r] + bias_v) * p.scale;
        if (OF32) ((float*)p.C)[(size_t)(row + r) * E_ + col] = v;
        else      ((bf16_t*)p.C)[(size_t)(row + r) * E_ + col] = (bf16_t)v;
      }
    }
  }
}

// ---------------- pass 1: softmax stats Z = m + log(l) ---------------------
__global__ __launch_bounds__(256) void pass1_kernel(const bf16_t* __restrict__ Qp,
                                                    const bf16_t* __restrict__ Kp,
                                                    float* __restrict__ Z) {
  const int qc = blockIdx.x;
  const int bh = blockIdx.y;
  const int b = bh >> 4, h = bh & 15;
  const int tid = threadIdx.x;
  const int wave = tid >> 6, lane = tid & 63;
  const int ln = lane & 15, qd = lane >> 4;
  const size_t rowbase = (size_t)b * S_;
  const int qbase = qc * 64 + wave * 16;

  bf16x8 qf[2];
#pragma unroll
  for (int db = 0; db < 2; db++)
    qf[db] = *(const bf16x8*)&Qp[(rowbase + qbase + ln) * E_ + h * 64 + db * 32 + qd * 8];

  float m[4], l[4];
#pragma unroll
  for (int r = 0; r < 4; r++) { m[r] = -1e30f; l[r] = 0.f; }

  for (int kt = 0; kt < S_ / 64; kt++) {
    bf16x8 kf[4][2];
#pragma unroll
    for (int nt = 0; nt < 4; nt++)
#pragma unroll
      for (int db = 0; db < 2; db++)
        kf[nt][db] = *(const bf16x8*)&Kp[(rowbase + kt * 64 + nt * 16 + ln) * E_ + h * 64 + db * 32 + qd * 8];
    f32x4 sc[4];
#pragma unroll
    for (int nt = 0; nt < 4; nt++) {
      f32x4 c0 = {0.f, 0.f, 0.f, 0.f};
      c0 = mfma16(qf[0], kf[nt][0], c0);
      sc[nt] = mfma16(qf[1], kf[nt][1], c0);
    }
#pragma unroll
    for (int r = 0; r < 4; r++) {
      float tmax = fmaxf(fmaxf(sc[0][r], sc[1][r]), fmaxf(sc[2][r], sc[3][r]));
      float mn = fmaxf(m[r], tmax);
      float add = __expf(sc[0][r] - mn) + __expf(sc[1][r] - mn) +
                  __expf(sc[2][r] - mn) + __expf(sc[3][r] - mn);
      l[r] = l[r] * __expf(m[r] - mn) + add;
      m[r] = mn;
    }
  }
#pragma unroll
  for (int r = 0; r < 4; r++) {
    float mm = m[r], ll = l[r];
    for (int mask = 1; mask < 16; mask <<= 1) {
      float mo = __shfl_xor(mm, mask);
      float lo = __shfl_xor(ll, mask);
      float mn = fmaxf(mm, mo);
      ll = ll * __expf(mm - mn) + lo * __expf(mo - mn);
      mm = mn;
    }
    if (ln == 0) {
      int q = qbase + qd * 4 + r;
      Z[(size_t)bh * S_ + q] = mm + __logf(ll);
    }
  }
}

// ---------------- pass 2: 3-stage MFMA pipeline ----------------------------
// 512 blocks x 512 thr (8 waves); block = (b, qt). No duplicated work.
// A : wave w -> src heads w, w+8: P[q=16][k=32][h=16] bf16 (normalized probs)
// B1: wave w -> keys 4w..4w+3: mixed[g][q][k] = (mix_hi+mix_lo) @ P  (bf16 MFMA)
// B2: wave w -> out-heads 2w, 2w+1: ctx += mixed @ V  (bf16 MFMA)
__global__ __launch_bounds__(512, 4) void pass2_kernel(const bf16_t* __restrict__ Qp,
                                                       const bf16_t* __restrict__ Kp,
                                                       const bf16_t* __restrict__ Vt,
                                                       const float* __restrict__ Z,
                                                       const bf16_t* __restrict__ mixh,
                                                       const bf16_t* __restrict__ mixl,
                                                       bf16_t* __restrict__ ctx) {
  const int id = blockIdx.x;            // 0..511
  const int b = id & 1;
  const int qt = id >> 1;               // 0..255, S_/16=128 per b
  const int q0 = (qt & 127) * 16;

  const int tid = threadIdx.x;
  const int wave = tid >> 6, lane = tid & 63;
  const int ln = lane & 15, qd = lane >> 4;

  __shared__ __align__(16) bf16_t Pl[16 * PQS + 16];   // [q][k][h] + guard
  __shared__ __align__(16) bf16_t MX[16 * 16 * MXS];   // [g][q][k-stride]

  // ---- zero-init Pl (pads + OOB guard read as 0, never NaN; one-time)
  bf16x8 pz = {0, 0, 0, 0, 0, 0, 0, 0};
  for (int i = tid; i < (16 * PQS + 16) / 8; i += 512)
    ((bf16x8*)Pl)[i] = pz;

  const size_t rowbase = (size_t)b * S_;

  // stage-A persistent state: heads hh = wave + 8e
  bf16x8 qf[2][2];
  float Zl[2];
#pragma unroll
  for (int e = 0; e < 2; e++) {
    const int hh = wave + e * 8;
#pragma unroll
    for (int db = 0; db < 2; db++)
      qf[e][db] = *(const bf16x8*)&Qp[(rowbase + q0 + ln) * E_ + hh * 64 + db * 32 + qd * 8];
    Zl[e] = Z[((size_t)(b * H_ + hh)) * S_ + q0 + ln];
  }

  // B1 A-operand: mix rows, m=ln (=g), k=h=qd*8+j valid for qd<2, else 0
  bf16x8 mixA_hi = pz, mixA_lo = pz;
  if (qd < 2) {
    mixA_hi = *(const bf16x8*)&mixh[ln * 16 + qd * 8];
    mixA_lo = *(const bf16x8*)&mixl[ln * 16 + qd * 8];
  }

  f32x4 z4 = {0.f, 0.f, 0.f, 0.f};
  f32x4 cacc[2][4];
#pragma unroll
  for (int t = 0; t < 2; t++)
#pragma unroll
    for (int nt = 0; nt < 4; nt++) cacc[t][nt] = z4;

  __syncthreads();   // Pl zero-init visible to all

  for (int ks = 0; ks < S_ / 32; ks++) {
    const int kb = ks * 32;
    // ---- stage A: P for src heads wave, wave+8
#pragma unroll
    for (int e = 0; e < 2; e++) {
      const int hh = wave + e * 8;
      bf16x8 kf[2][2];
#pragma unroll
      for (int n2 = 0; n2 < 2; n2++)
#pragma unroll
        for (int db = 0; db < 2; db++)
          kf[n2][db] = *(const bf16x8*)&Kp[(rowbase + kb + n2 * 16 + ln) * E_ + hh * 64 + db * 32 + qd * 8];
#pragma unroll
      for (int n2 = 0; n2 < 2; n2++) {
        f32x4 c0 = {-Zl[e], -Zl[e], -Zl[e], -Zl[e]};
        c0 = mfma16(kf[n2][0], qf[e][0], c0);
        c0 = mfma16(kf[n2][1], qf[e][1], c0);
        // D: col=q=ln, row=k_local=n2*16+qd*4+r  -> P[q][k][h]
#pragma unroll
        for (int r = 0; r < 4; r++)
          Pl[ln * PQS + (n2 * 16 + qd * 4 + r) * PKS + hh] = (bf16_t)__expf(c0[r]);
      }
    }
    __syncthreads();
    // ---- stage B1: mixed = mix @ P per key (this wave: keys 4w..4w+3)
#pragma unroll
    for (int j4 = 0; j4 < 4; j4++) {
      const int kk = wave * 4 + j4;
      // B-operand: n=q=ln, k-dim h=qd*8+j (qd>=2 -> zeroed pad / finite * 0)
      bf16x8 pfrag = *(const bf16x8*)&Pl[ln * PQS + kk * PKS + qd * 8];
      f32x4 d = mfma16(mixA_hi, pfrag, z4);
      d = mfma16(mixA_lo, pfrag, d);
      // D: col=q=ln, row=g=qd*4+r -> MX[g][q][kk]
#pragma unroll
      for (int r = 0; r < 4; r++)
        MX[((qd * 4 + r) * 16 + ln) * MXS + kk] = (bf16_t)d[r];
    }
    __syncthreads();
    // ---- stage B2: PV for out-heads 2w, 2w+1
#pragma unroll
    for (int t = 0; t < 2; t++) {
      const int g = wave * 2 + t;
      bf16x8 afrag = *(const bf16x8*)&MX[(g * 16 + ln) * MXS + qd * 8];
      const bf16_t* Vrow = &Vt[((size_t)((b * H_ + g) * 64)) * S_];
#pragma unroll
      for (int nt = 0; nt < 4; nt++) {
        bf16x8 vf = *(const bf16x8*)&Vrow[(size_t)(nt * 16 + ln) * S_ + kb + qd * 8];
        cacc[t][nt] = mfma16(afrag, vf, cacc[t][nt]);
      }
    }
    // no 3rd barrier: next bar1 separates B2's MX reads from next B1's writes;
    // bar2 separates B1's Pl reads from next A's Pl writes.
  }
#pragma unroll
  for (int t = 0; t < 2; t++) {
    const int g = wave * 2 + t;
#pragma unroll
    for (int nt = 0; nt < 4; nt++)
#pragma unroll
      for (int r = 0; r < 4; r++)
        ctx[(rowbase + q0 + qd * 4 + r) * E_ + g * 64 + nt * 16 + ln] = (bf16_t)cacc[t][nt][r];
  }
}

// ---------------------------------------------------------------------------
extern "C" void kernel_launch(void* const* d_in, const int* in_sizes, int n_in,
                              void* d_out, int out_size, void* d_ws, size_t ws_size,
                              hipStream_t stream) {
  const float* query = (const float*)d_in[0];
  const float* key_  = (const float*)d_in[1];
  const float* value = (const float*)d_in[2];
  const float* Wq = (const float*)d_in[3];
  const float* bq = (const float*)d_in[4];
  const float* Wk = (const float*)d_in[5];
  const float* bk = (const float*)d_in[6];
  const float* Wv = (const float*)d_in[7];
  const float* bv = (const float*)d_in[8];
  const float* hm = (const float*)d_in[9];
  const float* Wo = (const float*)d_in[10];
  const float* bo = (const float*)d_in[11];
  float* out = (float*)d_out;

  char* ws = (char*)d_ws;
  size_t off = 0;
  auto alloc = [&](size_t bytes) -> void* {
    void* p = ws + off;
    off += (bytes + 255) & ~(size_t)255;
    return p;
  };
  bf16_t* MIXH = (bf16_t*)alloc(256 * 2);
  bf16_t* MIXL = (bf16_t*)alloc(256 * 2);
  float*  Zb   = (float*) alloc((size_t)B_ * H_ * S_ * 4);  // 256 KB
  bf16_t* Qp   = (bf16_t*)alloc((size_t)B_ * S_ * E_ * 2);  // 8.4 MB (scaled 1/8)
  bf16_t* Kp   = (bf16_t*)alloc((size_t)B_ * S_ * E_ * 2);  // 8.4 MB
  bf16_t* Vp   = (bf16_t*)alloc((size_t)B_ * S_ * E_ * 2);  // 8.4 MB
  bf16_t* Vtt  = (bf16_t*)alloc((size_t)B_ * S_ * E_ * 2);  // 8.4 MB [b,g,d,s]
  bf16_t* CTX  = Vp;  // alias: Vp dead after transpose_v (stream-ordered)
  (void)in_sizes; (void)n_in; (void)out_size; (void)ws_size;

  mix_kernel<<<1, 256, 0, stream>>>(hm, MIXH, MIXL);

  GemmSec sq{query, bq, Wq, Qp, 0.125f};
  GemmSec sk{key_,  bk, Wk, Kp, 1.f};
  GemmSec sv{value, bv, Wv, Vp, 1.f};
  gemm_kernel<true, false><<<dim3(8, 32, 3), 256, 0, stream>>>(sq, sk, sv);

  transpose_v_kernel<<<dim3(64, 2, 32), 256, 0, stream>>>(Vp, Vtt);
  pass1_kernel<<<dim3(32, 32, 1), 256, 0, stream>>>(Qp, Kp, Zb);
  pass2_kernel<<<dim3(512, 1, 1), 512, 0, stream>>>(Qp, Kp, Vtt, Zb, MIXH, MIXL, CTX);

  GemmSec so{CTX, bo, Wo, out, 1.f};
  gemm_kernel<false, true><<<dim3(8, 32, 1), 256, 0, stream>>>(so, so, so);
}